// Round 9
// baseline (185.790 us; speedup 1.0000x reference)
//
#include <hip/hip_runtime.h>
#include <math.h>
#include <stdint.h>

#define VOCAB 100000
#define NB    1024
#define QLEN  32
#define DLEN  256
#define EMBED 128
#define KNUM  11

typedef __attribute__((ext_vector_type(8))) short bf16x8;   // 8 bf16 = 4 VGPRs
typedef __attribute__((ext_vector_type(4))) float f32x4;

// Gaussian chain: mus -0.9..0.9 step 0.2 (sigma 0.1) + exact mu=1 sigma=.001
#define HALF_L2E 0.7213475204444817f   // 0.5*log2(e)
#define TWO_L2E  2.8853900817779268f   // 2*log2(e)
#define EM4      0.018315638888734179f // e^-4

#define SSTR  68                 // fallback sim stride
#define SHALF (16 * SSTR)
#define SST9  36                 // pair9 sim stride (32 cols + 4 pad, 16B-aligned rows)

// ---------- prepass: fp32 table -> bf16 table ----
__global__ __launch_bounds__(256)
void cvt_table(const float* __restrict__ emb, ushort* __restrict__ ebf)
{
    const int row = blockIdx.x * 8 + (threadIdx.x >> 5);
    const int l32 = threadIdx.x & 31;
    const float4 v = *((const float4*)(emb + (size_t)row * EMBED) + l32);
    union { float f; unsigned u; } x0, x1, x2, x3;
    x0.f = v.x; x1.f = v.y; x2.f = v.z; x3.f = v.w;
    const unsigned r0 = x0.u + 0x8000u, r1 = x1.u + 0x8000u;  // round-half-up
    const unsigned r2 = x2.u + 0x8000u, r3 = x3.u + 0x8000u;
    uint2 packed;
    packed.x = (r0 >> 16) | (r1 & 0xFFFF0000u);
    packed.y = (r2 >> 16) | (r3 & 0xFFFF0000u);
    *((uint2*)(ebf + (size_t)row * EMBED) + l32) = packed;
}

// the 11-kernel exp chain on 4 sims (byte-identical across rounds)
__device__ __forceinline__ void chain4(const f32x4 sv, float (&ksum)[KNUM])
{
    #pragma unroll
    for (int e = 0; e < 4; ++e) {
        const float s  = sv[e];
        const float z  = fmaf(s, 10.f, -1.f);
        const float e0 = exp2f(-HALF_L2E * (z * z));
        float ru = exp2f(fmaf(z,  TWO_L2E, -TWO_L2E));
        float rd = exp2f(fmaf(z, -TWO_L2E, -TWO_L2E));
        ksum[5] += e0;
        float tt = e0;
        tt *= ru; ksum[6] += tt; ru *= EM4;
        tt *= ru; ksum[7] += tt; ru *= EM4;
        tt *= ru; ksum[8] += tt; ru *= EM4;
        tt *= ru; ksum[9] += tt;
        tt = e0;
        tt *= rd; ksum[4] += tt; rd *= EM4;
        tt *= rd; ksum[3] += tt; rd *= EM4;
        tt *= rd; ksum[2] += tt; rd *= EM4;
        tt *= rd; ksum[1] += tt; rd *= EM4;
        tt *= rd; ksum[0] += tt;
        // exact kernel (sigma=.001): ==1 iff token match (bf16 self-sim
        // 1+-3e-6; non-match needs cos>0.995 ~ 11 sigma)
        ksum[10] += (s > 0.995f) ? 1.f : 0.f;
    }
}

// sumsq of 8 bf16 lane-local elements (bit-exact bf16->f32 via <<16)
__device__ __forceinline__ float sumsq8(const bf16x8 v, float acc)
{
    #pragma unroll
    for (int e = 0; e < 8; ++e) {
        union { unsigned u; float f; } g;
        g.u = ((unsigned)(unsigned short)v[e]) << 16;
        acc = fmaf(g.f, g.f, acc);
    }
    return acc;
}

// issue the 8 frag gathers of one half-unit (2 doc tiles) into bb regs
__device__ __forceinline__ void issue_frags9(const ushort* __restrict__ ebf,
                                             int i0, int i1, int quad,
                                             bf16x8 (&b0)[4], bf16x8 (&b1)[4])
{
    const ushort* p0 = ebf + (size_t)i0 * EMBED + quad * 8;
    const ushort* p1 = ebf + (size_t)i1 * EMBED + quad * 8;
    #pragma unroll
    for (int kk = 0; kk < 4; ++kk) {
        b0[kk] = *(const bf16x8*)(p0 + kk * 32);
        b1[kk] = *(const bf16x8*)(p1 + kk * 32);
    }
}

// One half-unit: {issue ids(u+2)} -> MFMA+norms+sims(u) -> {issue frags(u+1)}
// -> fence -> pool(u). Loads issued here stay in flight THROUGH the pool
// phase (first use is next call's MFMA); lgkmcnt(0) does not drain vmcnt.
__device__ __forceinline__ void half_unit9(
    const ushort* __restrict__ ebf, const int* __restrict__ doc,
    int l15, int quad,
    int u2, int& n2a, int& n2b,            // ids two-ahead (skip if u2<0)
    int nxa, int nxb, bool hasNext,        // ids for frags(u+1)
    bf16x8 (&b0)[4], bf16x8 (&b1)[4],
    const bf16x8 (&a0)[4], const bf16x8 (&a1)[4],
    const float (&riq)[2][4],
    float* __restrict__ s_sim, float (*__restrict__ stot)[12])
{
    if (u2 >= 0) {                          // ids two half-units ahead
        n2a = doc[u2 * 32 + l15];
        n2b = doc[u2 * 32 + 16 + l15];
    }

    // ---- MFMA (waits only on own bb) + doc norms + sims -> LDS ----
    float dn0 = 0.f, dn1 = 0.f;
    f32x4 p00 = {0.f,0.f,0.f,0.f}, p01 = p00, p10 = p00, p11 = p00;
    #pragma unroll
    for (int kk = 0; kk < 4; ++kk) {
        p00 = __builtin_amdgcn_mfma_f32_16x16x32_bf16(a0[kk], b0[kk], p00, 0, 0, 0);
        p10 = __builtin_amdgcn_mfma_f32_16x16x32_bf16(a1[kk], b0[kk], p10, 0, 0, 0);
        dn0 = sumsq8(b0[kk], dn0);
        p01 = __builtin_amdgcn_mfma_f32_16x16x32_bf16(a0[kk], b1[kk], p01, 0, 0, 0);
        p11 = __builtin_amdgcn_mfma_f32_16x16x32_bf16(a1[kk], b1[kk], p11, 0, 0, 0);
        dn1 = sumsq8(b1[kk], dn1);
    }
    dn0 += __shfl_xor(dn0, 16); dn0 += __shfl_xor(dn0, 32);
    dn1 += __shfl_xor(dn1, 16); dn1 += __shfl_xor(dn1, 32);
    const float idn0 = __builtin_amdgcn_rsqf(dn0);
    const float idn1 = __builtin_amdgcn_rsqf(dn1);
    #pragma unroll
    for (int r = 0; r < 4; ++r) {
        s_sim[(     quad * 4 + r) * SST9 +      l15] = p00[r] * riq[0][r] * idn0;
        s_sim[(16 + quad * 4 + r) * SST9 +      l15] = p10[r] * riq[1][r] * idn0;
        s_sim[(     quad * 4 + r) * SST9 + 16 + l15] = p01[r] * riq[0][r] * idn1;
        s_sim[(16 + quad * 4 + r) * SST9 + 16 + l15] = p11[r] * riq[1][r] * idn1;
    }

    // ---- prefetch next half-unit (bb regs free: consumed above) ----
    if (hasNext) issue_frags9(ebf, nxa, nxb, quad, b0, b1);

    // sims visible (in-wave LDS order); vmcnt NOT drained; nothing crosses
    asm volatile("s_waitcnt lgkmcnt(0)" ::: "memory");
    __builtin_amdgcn_sched_barrier(0);

    // ---- pool: row l15 per mt, col slice quad*8..+7 (32 cols total) ----
    #pragma unroll
    for (int mt = 0; mt < 2; ++mt) {
        const float* rp = s_sim + (mt * 16 + l15) * SST9 + quad * 8;
        float ksum[KNUM];
        #pragma unroll
        for (int k = 0; k < KNUM; ++k) ksum[k] = 0.f;
        chain4(*(const f32x4*)rp, ksum);
        chain4(*(const f32x4*)(rp + 4), ksum);
        #pragma unroll
        for (int k = 0; k < KNUM; ++k) {
            ksum[k] += __shfl_xor(ksum[k], 16);
            ksum[k] += __shfl_xor(ksum[k], 32);
        }
        if (quad == 0) {
            #pragma unroll
            for (int k = 0; k < KNUM; ++k)
                stot[mt * 16 + l15][k] += ksum[k];   // wave-private: no atomic
        }
    }
    __builtin_amdgcn_sched_barrier(0);   // next unit's ds_writes stay below
}

// ---------------------------------------------------------------------------
// Round-9: 1-wave blocks (64 thr), zero barriers, continuous-MLP pipeline.
// Block owns one (b,pair): 32 q rows x 256 doc rows = 8 half-units of
// 2 tiles. During every pool phase the next half-unit's 8 frag loads (+2
// id loads two-ahead) are in flight -> time-averaged misses/wave ~8 vs ~5
// for the one-shot r4 burst, and 8 waves/CU co-resident (VGPR<=128).
__global__ __launch_bounds__(64, 2)
void knrm_pair9(const ushort* __restrict__ ebf,
                const float* __restrict__ mlp_w,
                const int* __restrict__ q1, const int* __restrict__ d1,
                const int* __restrict__ q2, const int* __restrict__ d2,
                float* __restrict__ logits)
{
    const int b    = blockIdx.x;
    const int pair = blockIdx.y;
    const int t    = threadIdx.x;          // 0..63, one wave
    const int l15  = t & 15;
    const int quad = t >> 4;

    const int* __restrict__ qry = (pair == 0 ? q1 : q2) + b * QLEN;
    const int* __restrict__ doc = (pair == 0 ? d1 : d2) + b * DLEN;

    __shared__ __align__(16) float s_sim[32 * SST9];   // 4608 B
    __shared__ float s_tot[QLEN][12];                  // 1536 B

    // ids for half-units 0 and 1 (A/B/C rotate; dum absorbs dead writes)
    int ia0 = doc[l15],      ia1 = doc[16 + l15];      // ids(0)
    int ib0 = doc[32 + l15], ib1 = doc[48 + l15];      // ids(1)
    int ic0, ic1, dum0, dum1;

    // ---- q: ids, frags, in-register norms (r8-identical values) ----
    const int qid0 = qry[l15], qid1 = qry[l15 + 16];
    bf16x8 a0[4], a1[4];
    float qn0 = 0.f, qn1 = 0.f;
    {
        const ushort* p0 = ebf + (size_t)qid0 * EMBED + quad * 8;
        const ushort* p1 = ebf + (size_t)qid1 * EMBED + quad * 8;
        #pragma unroll
        for (int kk = 0; kk < 4; ++kk) {
            a0[kk] = *(const bf16x8*)(p0 + kk * 32);
            a1[kk] = *(const bf16x8*)(p1 + kk * 32);
            qn0 = sumsq8(a0[kk], qn0);
            qn1 = sumsq8(a1[kk], qn1);
        }
    }
    qn0 += __shfl_xor(qn0, 16); qn0 += __shfl_xor(qn0, 32);
    qn1 += __shfl_xor(qn1, 16); qn1 += __shfl_xor(qn1, 32);
    float riq[2][4];
    #pragma unroll
    for (int r = 0; r < 4; ++r) {
        riq[0][r] = __builtin_amdgcn_rsqf(__shfl(qn0, quad * 4 + r));
        riq[1][r] = __builtin_amdgcn_rsqf(__shfl(qn1, quad * 4 + r));
    }

    // zero s_tot (wave-private; in-wave LDS order suffices, no barrier)
    #pragma unroll
    for (int i = t; i < QLEN * 12; i += 64) ((float*)s_tot)[i] = 0.f;

    // frags(0)
    bf16x8 b0[4], b1[4];
    issue_frags9(ebf, ia0, ia1, quad, b0, b1);

    // 8 half-units; id sets rotate A,B,C (liveness verified per-call)
    half_unit9(ebf, doc, l15, quad,  2, ic0, ic1, ib0, ib1, true,  b0, b1, a0, a1, riq, s_sim, s_tot); // u0
    half_unit9(ebf, doc, l15, quad,  3, ia0, ia1, ic0, ic1, true,  b0, b1, a0, a1, riq, s_sim, s_tot); // u1
    half_unit9(ebf, doc, l15, quad,  4, ib0, ib1, ia0, ia1, true,  b0, b1, a0, a1, riq, s_sim, s_tot); // u2
    half_unit9(ebf, doc, l15, quad,  5, ic0, ic1, ib0, ib1, true,  b0, b1, a0, a1, riq, s_sim, s_tot); // u3
    half_unit9(ebf, doc, l15, quad,  6, ia0, ia1, ic0, ic1, true,  b0, b1, a0, a1, riq, s_sim, s_tot); // u4
    half_unit9(ebf, doc, l15, quad,  7, ib0, ib1, ia0, ia1, true,  b0, b1, a0, a1, riq, s_sim, s_tot); // u5
    half_unit9(ebf, doc, l15, quad, -1, dum0, dum1, ib0, ib1, true,  b0, b1, a0, a1, riq, s_sim, s_tot); // u6 (ids(7) in B)
    half_unit9(ebf, doc, l15, quad, -1, dum0, dum1, 0, 0,     false, b0, b1, a0, a1, riq, s_sim, s_tot); // u7

    // ---- final: log1p + dot + in-wave reduce, lane 0 writes ----
    float wk[KNUM];
    #pragma unroll
    for (int k = 0; k < KNUM; ++k) wk[k] = mlp_w[k];
    float c = 0.f;
    if (t < QLEN) {
        #pragma unroll
        for (int k = 0; k < KNUM; ++k) c += wk[k] * log1pf(s_tot[t][k]);
    }
    #pragma unroll
    for (int m = 1; m < 64; m <<= 1) c += __shfl_xor(c, m);
    if (t == 0) logits[pair * NB + b] = c;   // mlp bias cancels in l1-l2
}

// ---------------------------------------------------------------------------
// fallback helper: fp32 -> bf16 frag + norm of rounded values
__device__ __forceinline__ bf16x8 cvt8(const float* p, float& nacc)
{
    uint4 a = *((const uint4*)p);
    uint4 b = *((const uint4*)(p + 4));
    unsigned u[8] = {a.x, a.y, a.z, a.w, b.x, b.y, b.z, b.w};
    bf16x8 r;
    #pragma unroll
    for (int i = 0; i < 8; ++i) {
        const unsigned q = u[i] + 0x8000u;
        r[i] = (short)(q >> 16);
        union { unsigned uu; float ff; } g; g.uu = q & 0xFFFF0000u;
        nacc = fmaf(g.ff, g.ff, nacc);
    }
    return r;
}

__device__ __forceinline__ void pool_half(float* __restrict__ wtile,
                                          const f32x4* __restrict__ a,
                                          const float* __restrict__ riq,
                                          const float* __restrict__ idn,
                                          float (*__restrict__ stot)[12],
                                          int mtbase, int l15, int quad)
{
    #pragma unroll
    for (int nt = 0; nt < 4; ++nt)
        #pragma unroll
        for (int r = 0; r < 4; ++r)
            wtile[(quad * 4 + r) * SSTR + nt * 16 + l15] = a[nt][r] * riq[r] * idn[nt];

    const float* rp = wtile + l15 * SSTR + quad * 16;
    float ksum[KNUM];
    #pragma unroll
    for (int k = 0; k < KNUM; ++k) ksum[k] = 0.f;
    #pragma unroll
    for (int i = 0; i < 4; ++i)
        chain4(*(const f32x4*)(rp + 4 * i), ksum);
    #pragma unroll
    for (int k = 0; k < KNUM; ++k) {
        ksum[k] += __shfl_xor(ksum[k], 16);
        ksum[k] += __shfl_xor(ksum[k], 32);
    }
    if (quad == 0) {
        #pragma unroll
        for (int k = 0; k < KNUM; ++k)
            atomicAdd(&stot[mtbase + l15][k], ksum[k]);
    }
}

// Legacy fp32 fallback (small workspace).
__global__ __launch_bounds__(256, 4)
void knrm_pair_fb(const float* __restrict__ emb,
                  const float* __restrict__ mlp_w,
                  const int* __restrict__ q1, const int* __restrict__ d1,
                  const int* __restrict__ q2, const int* __restrict__ d2,
                  float* __restrict__ logits)
{
    const int b    = blockIdx.x;
    const int pair = blockIdx.y;
    const int t    = threadIdx.x;
    const int w    = t >> 6;
    const int l15  = t & 15;
    const int quad = (t & 63) >> 4;

    const int* __restrict__ qry = (pair == 0 ? q1 : q2) + b * QLEN;
    const int* __restrict__ doc = (pair == 0 ? d1 : d2) + b * DLEN;

    __shared__ __align__(16) float s_sim[4 * SHALF];
    __shared__ float s_tot[QLEN][12];

    #pragma unroll
    for (int i = t; i < QLEN * 12; i += 256) ((float*)s_tot)[i] = 0.f;
    __syncthreads();

    const int qid0 = qry[l15], qid1 = qry[l15 + 16];
    int did[4];
    #pragma unroll
    for (int nt = 0; nt < 4; ++nt) did[nt] = doc[(w * 4 + nt) * 16 + l15];

    f32x4 acc[2][4];
    #pragma unroll
    for (int mt = 0; mt < 2; ++mt)
        #pragma unroll
        for (int nt = 0; nt < 4; ++nt)
            acc[mt][nt] = (f32x4){0.f, 0.f, 0.f, 0.f};

    float idn[4], riq[2][4];
    float* wtile = s_sim + w * SHALF;

    {
        float qn2[2] = {0.f, 0.f}, dn2[4] = {0.f, 0.f, 0.f, 0.f};
        const float* qp0 = emb + (size_t)qid0 * EMBED + quad * 8;
        const float* qp1 = emb + (size_t)qid1 * EMBED + quad * 8;
        #pragma unroll
        for (int kk = 0; kk < 4; ++kk) {
            const bf16x8 a0 = cvt8(qp0 + kk * 32, qn2[0]);
            const bf16x8 a1 = cvt8(qp1 + kk * 32, qn2[1]);
            #pragma unroll
            for (int nt = 0; nt < 4; ++nt) {
                const bf16x8 bb = cvt8(emb + (size_t)did[nt] * EMBED + quad * 8 + kk * 32, dn2[nt]);
                acc[0][nt] = __builtin_amdgcn_mfma_f32_16x16x32_bf16(a0, bb, acc[0][nt], 0, 0, 0);
                acc[1][nt] = __builtin_amdgcn_mfma_f32_16x16x32_bf16(a1, bb, acc[1][nt], 0, 0, 0);
            }
        }
        #pragma unroll
        for (int i = 0; i < 2; ++i) {
            qn2[i] += __shfl_xor(qn2[i], 16);
            qn2[i] += __shfl_xor(qn2[i], 32);
        }
        #pragma unroll
        for (int nt = 0; nt < 4; ++nt) {
            dn2[nt] += __shfl_xor(dn2[nt], 16);
            dn2[nt] += __shfl_xor(dn2[nt], 32);
            idn[nt] = __builtin_amdgcn_rsqf(dn2[nt]);
        }
        #pragma unroll
        for (int r = 0; r < 4; ++r) {
            riq[0][r] = __builtin_amdgcn_rsqf(__shfl(qn2[0], quad * 4 + r));
            riq[1][r] = __builtin_amdgcn_rsqf(__shfl(qn2[1], quad * 4 + r));
        }
    }

    pool_half(wtile, acc[0], riq[0], idn, s_tot, 0,  l15, quad);
    pool_half(wtile, acc[1], riq[1], idn, s_tot, 16, l15, quad);
    __syncthreads();

    if (t < QLEN) {
        float c = 0.f;
        #pragma unroll
        for (int k = 0; k < KNUM; ++k) c += mlp_w[k] * log1pf(s_tot[t][k]);
        #pragma unroll
        for (int mm = 1; mm < 32; mm <<= 1) c += __shfl_xor(c, mm);
        if (t == 0) logits[pair * NB + b] = c;
    }
}

__global__ __launch_bounds__(256)
void knrm_combine(const float* __restrict__ logits, float* __restrict__ out)
{
    const int i = blockIdx.x * blockDim.x + threadIdx.x;
    if (i < NB) {
        const float d = logits[i] - logits[NB + i];
        out[i] = 1.f / (1.f + __expf(-d));
    }
}

extern "C" void kernel_launch(void* const* d_in, const int* in_sizes, int n_in,
                              void* d_out, int out_size, void* d_ws, size_t ws_size,
                              hipStream_t stream)
{
    const float* emb   = (const float*)d_in[0];
    const float* mlp_w = (const float*)d_in[1];
    // mlp_b (d_in[2]) unused: cancels in logits1 - logits2
    const int* q1 = (const int*)d_in[3];
    const int* d1 = (const int*)d_in[4];
    const int* q2 = (const int*)d_in[5];
    const int* d2 = (const int*)d_in[6];

    float* out = (float*)d_out;

    const size_t need = 2 * NB * 4                       // logits
                      + (size_t)VOCAB * EMBED * 2 + 256; // bf16 table
    if (ws_size >= need) {
        float*  logits = (float*)d_ws;
        ushort* ebf    = (ushort*)(logits + 2 * NB);
        cvt_table<<<VOCAB / 8, 256, 0, stream>>>(emb, ebf);
        knrm_pair9<<<dim3(NB, 2), 64, 0, stream>>>(ebf, mlp_w,
                                                   q1, d1, q2, d2, logits);
    } else {
        float* logits = (float*)d_ws;
        knrm_pair_fb<<<dim3(NB, 2), 256, 0, stream>>>(emb, mlp_w,
                                                      q1, d1, q2, d2, logits);
    }
    knrm_combine<<<(NB + 255) / 256, 256, 0, stream>>>((float*)d_ws, out);
}

// Round 10
// 140.240 us; speedup vs baseline: 1.3248x; 1.3248x over previous
//
#include <hip/hip_runtime.h>
#include <math.h>
#include <stdint.h>

#define VOCAB 100000
#define NB    1024
#define QLEN  32
#define DLEN  256
#define EMBED 128
#define KNUM  11

typedef __attribute__((ext_vector_type(8))) short bf16x8;   // 8 bf16 = 4 VGPRs
typedef __attribute__((ext_vector_type(4))) float f32x4;

// Gaussian chain: mus -0.9..0.9 step 0.2 (sigma 0.1) + exact mu=1 sigma=.001
#define HALF_L2E 0.7213475204444817f   // 0.5*log2(e)
#define TWO_L2E  2.8853900817779268f   // 2*log2(e)
#define EM4      0.018315638888734179f // e^-4

// Wave-private sim half-tile: [m=16][n=64], row stride 68 (16B-aligned rows,
// 2-way bank aliasing = free per m136).
#define SSTR  68
#define SHALF (16 * SSTR)

// ---------- prepass: fp32 table -> bf16 table + bf16-consistent inv-norms ----
__global__ __launch_bounds__(256)
void cvt_table(const float* __restrict__ emb, ushort* __restrict__ ebf,
               float* __restrict__ inorm)
{
    const int row = blockIdx.x * 8 + (threadIdx.x >> 5);
    const int l32 = threadIdx.x & 31;
    const float4 v = *((const float4*)(emb + (size_t)row * EMBED) + l32);
    union { float f; unsigned u; } x0, x1, x2, x3;
    x0.f = v.x; x1.f = v.y; x2.f = v.z; x3.f = v.w;
    const unsigned r0 = x0.u + 0x8000u, r1 = x1.u + 0x8000u;  // round-half-up
    const unsigned r2 = x2.u + 0x8000u, r3 = x3.u + 0x8000u;
    uint2 packed;
    packed.x = (r0 >> 16) | (r1 & 0xFFFF0000u);
    packed.y = (r2 >> 16) | (r3 & 0xFFFF0000u);
    *((uint2*)(ebf + (size_t)row * EMBED) + l32) = packed;
    x0.u = r0 & 0xFFFF0000u; x1.u = r1 & 0xFFFF0000u;
    x2.u = r2 & 0xFFFF0000u; x3.u = r3 & 0xFFFF0000u;
    float n = x0.f * x0.f + x1.f * x1.f + x2.f * x2.f + x3.f * x3.f;
    #pragma unroll
    for (int m = 1; m < 32; m <<= 1) n += __shfl_xor(n, m);
    if (l32 == 0) inorm[row] = __builtin_amdgcn_rsqf(n);
}

// ---------------------------------------------------------------------------
// fallback helper: fp32 -> bf16 frag + norm of rounded values
__device__ __forceinline__ bf16x8 cvt8(const float* p, float& nacc)
{
    uint4 a = *((const uint4*)p);
    uint4 b = *((const uint4*)(p + 4));
    unsigned u[8] = {a.x, a.y, a.z, a.w, b.x, b.y, b.z, b.w};
    bf16x8 r;
    #pragma unroll
    for (int i = 0; i < 8; ++i) {
        const unsigned q = u[i] + 0x8000u;
        r[i] = (short)(q >> 16);
        union { unsigned uu; float ff; } g; g.uu = q & 0xFFFF0000u;
        nacc = fmaf(g.ff, g.ff, nacc);
    }
    return r;
}

// pool one 16-row half-tile: write sims, exp-chain, reduce, atomic into s_tot
__device__ __forceinline__ void pool_half(float* __restrict__ wtile,
                                          const f32x4* __restrict__ a,   // [4] nt
                                          const float* __restrict__ riq, // [4] r
                                          const float* __restrict__ idn, // [4] nt
                                          float (*__restrict__ stot)[12],
                                          int mtbase, int l15, int quad)
{
    #pragma unroll
    for (int nt = 0; nt < 4; ++nt)
        #pragma unroll
        for (int r = 0; r < 4; ++r)
            wtile[(quad * 4 + r) * SSTR + nt * 16 + l15] = a[nt][r] * riq[r] * idn[nt];

    const float* rp = wtile + l15 * SSTR + quad * 16;   // row l15, chunk quad
    float ksum[KNUM];
    #pragma unroll
    for (int k = 0; k < KNUM; ++k) ksum[k] = 0.f;

    #pragma unroll
    for (int i = 0; i < 4; ++i) {
        const f32x4 sv = *((const f32x4*)(rp + 4 * i));
        #pragma unroll
        for (int e = 0; e < 4; ++e) {
            const float s  = sv[e];
            const float z  = fmaf(s, 10.f, -1.f);
            const float e0 = exp2f(-HALF_L2E * (z * z));
            float ru = exp2f(fmaf(z,  TWO_L2E, -TWO_L2E));
            float rd = exp2f(fmaf(z, -TWO_L2E, -TWO_L2E));
            ksum[5] += e0;
            float tt = e0;
            tt *= ru; ksum[6] += tt; ru *= EM4;
            tt *= ru; ksum[7] += tt; ru *= EM4;
            tt *= ru; ksum[8] += tt; ru *= EM4;
            tt *= ru; ksum[9] += tt;
            tt = e0;
            tt *= rd; ksum[4] += tt; rd *= EM4;
            tt *= rd; ksum[3] += tt; rd *= EM4;
            tt *= rd; ksum[2] += tt; rd *= EM4;
            tt *= rd; ksum[1] += tt; rd *= EM4;
            tt *= rd; ksum[0] += tt;
            // exact kernel (sigma=.001): ==1 iff token match (bf16 self-sim
            // 1+-3e-6; non-match needs cos>0.995 ~ 11 sigma)
            ksum[10] += (s > 0.995f) ? 1.f : 0.f;
        }
    }
    #pragma unroll
    for (int k = 0; k < KNUM; ++k) {
        ksum[k] += __shfl_xor(ksum[k], 16);
        ksum[k] += __shfl_xor(ksum[k], 32);
    }
    if (quad == 0) {
        #pragma unroll
        for (int k = 0; k < KNUM; ++k)
            atomicAdd(&stot[mtbase + l15][k], ksum[k]);
    }
}

// ---------------------------------------------------------------------------
// Round-4 structure (best verified: 49.7us dispatch, 141.7us total): legacy
// 4-wave shape + compiler-proof full load hoist. All 24 frag gathers issue
// back-to-back, pinned by asm volatile consumers (data dep -> loads stay
// above) + sched_barrier(0) (MFMAs stay below). One vmcnt wait point per
// wave with up to 24 loads outstanding.
__global__ __launch_bounds__(256, 3)
void knrm_pair4(const ushort* __restrict__ ebf,
                const float* __restrict__ inorm,
                const float* __restrict__ mlp_w,
                const int* __restrict__ q1, const int* __restrict__ d1,
                const int* __restrict__ q2, const int* __restrict__ d2,
                float* __restrict__ logits)
{
    const int b    = blockIdx.x;
    const int pair = blockIdx.y;
    const int t    = threadIdx.x;
    const int w    = t >> 6;        // wave id: doc tiles w*4..w*4+3
    const int l15  = t & 15;
    const int quad = (t & 63) >> 4;

    const int* __restrict__ qry = (pair == 0 ? q1 : q2) + b * QLEN;
    const int* __restrict__ doc = (pair == 0 ? d1 : d2) + b * DLEN;

    __shared__ __align__(16) float s_sim[4 * SHALF];   // 17408 B wave-private
    __shared__ float s_tot[QLEN][12];                  // 1536 B

    // ---- ids (independent, oldest vmem) ----
    const int qid0 = qry[l15], qid1 = qry[l15 + 16];
    int did[4];
    #pragma unroll
    for (int j = 0; j < 4; ++j) did[j] = doc[(w * 4 + j) * 16 + l15];

    // ---- all 24 fragment gathers, issued before any compute ----
    bf16x8 a0[4], a1[4], bbf[4][4];
    {
        const ushort* qp0 = ebf + (size_t)qid0 * EMBED + quad * 8;
        const ushort* qp1 = ebf + (size_t)qid1 * EMBED + quad * 8;
        #pragma unroll
        for (int kk = 0; kk < 4; ++kk) {
            a0[kk] = *(const bf16x8*)(qp0 + kk * 32);
            a1[kk] = *(const bf16x8*)(qp1 + kk * 32);
        }
        #pragma unroll
        for (int j = 0; j < 4; ++j) {
            const ushort* dp = ebf + (size_t)did[j] * EMBED + quad * 8;
            #pragma unroll
            for (int kk = 0; kk < 4; ++kk)
                bbf[j][kk] = *(const bf16x8*)(dp + kk * 32);
        }
    }
    // norm gathers: consumed only in pooling -> stay in flight through MFMA
    float idn[4];
    #pragma unroll
    for (int j = 0; j < 4; ++j) idn[j] = inorm[did[j]];
    float riq[2][4];
    #pragma unroll
    for (int r = 0; r < 4; ++r) {
        riq[0][r] = inorm[qry[quad * 4 + r]];
        riq[1][r] = inorm[qry[16 + quad * 4 + r]];
    }

    // zero s_tot while the gathers fly
    #pragma unroll
    for (int i = t; i < QLEN * 12; i += 256) ((float*)s_tot)[i] = 0.f;

    // ---- pin: loads can't sink below (data dep), MFMAs can't hoist above ----
    #pragma unroll
    for (int kk = 0; kk < 4; ++kk)
        asm volatile("" :: "v"(a0[kk]), "v"(a1[kk]));
    #pragma unroll
    for (int j = 0; j < 4; ++j)
        asm volatile("" :: "v"(bbf[j][0]), "v"(bbf[j][1]),
                          "v"(bbf[j][2]), "v"(bbf[j][3]));
    __builtin_amdgcn_sched_barrier(0);

    // ---- MFMA: 32 q-rows x 64 doc-cols x K=128 per wave ----
    f32x4 acc[2][4];
    #pragma unroll
    for (int mt = 0; mt < 2; ++mt)
        #pragma unroll
        for (int j = 0; j < 4; ++j)
            acc[mt][j] = (f32x4){0.f, 0.f, 0.f, 0.f};
    #pragma unroll
    for (int kk = 0; kk < 4; ++kk)
        #pragma unroll
        for (int j = 0; j < 4; ++j) {
            acc[0][j] = __builtin_amdgcn_mfma_f32_16x16x32_bf16(a0[kk], bbf[j][kk], acc[0][j], 0, 0, 0);
            acc[1][j] = __builtin_amdgcn_mfma_f32_16x16x32_bf16(a1[kk], bbf[j][kk], acc[1][j], 0, 0, 0);
        }

    __syncthreads();        // s_tot zeros visible before pooling atomics

    float* wtile = s_sim + w * SHALF;
    pool_half(wtile, acc[0], riq[0], idn, s_tot, 0,  l15, quad);
    pool_half(wtile, acc[1], riq[1], idn, s_tot, 16, l15, quad);
    __syncthreads();

    if (t < QLEN) {
        float c = 0.f;
        #pragma unroll
        for (int k = 0; k < KNUM; ++k) c += mlp_w[k] * log1pf(s_tot[t][k]);
        #pragma unroll
        for (int mm = 1; mm < 32; mm <<= 1) c += __shfl_xor(c, mm);
        if (t == 0) logits[pair * NB + b] = c;   // mlp bias cancels in l1-l2
    }
}

// Legacy kernel, kept as the small-workspace fallback (instantiated <false>).
template<bool PRE>
__global__ __launch_bounds__(256, 4)
void knrm_pair(const float* __restrict__ emb,
               const ushort* __restrict__ ebf,
               const float* __restrict__ inorm,
               const float* __restrict__ mlp_w,
               const int* __restrict__ q1, const int* __restrict__ d1,
               const int* __restrict__ q2, const int* __restrict__ d2,
               float* __restrict__ logits)
{
    const int b    = blockIdx.x;
    const int pair = blockIdx.y;
    const int t    = threadIdx.x;
    const int w    = t >> 6;
    const int l15  = t & 15;
    const int quad = (t & 63) >> 4;

    const int* __restrict__ qry = (pair == 0 ? q1 : q2) + b * QLEN;
    const int* __restrict__ doc = (pair == 0 ? d1 : d2) + b * DLEN;

    __shared__ __align__(16) float s_sim[4 * SHALF];
    __shared__ float s_tot[QLEN][12];

    #pragma unroll
    for (int i = t; i < QLEN * 12; i += 256) ((float*)s_tot)[i] = 0.f;
    __syncthreads();

    const int qid0 = qry[l15], qid1 = qry[l15 + 16];
    int did[4];
    #pragma unroll
    for (int nt = 0; nt < 4; ++nt) did[nt] = doc[(w * 4 + nt) * 16 + l15];

    f32x4 acc[2][4];
    #pragma unroll
    for (int mt = 0; mt < 2; ++mt)
        #pragma unroll
        for (int nt = 0; nt < 4; ++nt)
            acc[mt][nt] = (f32x4){0.f, 0.f, 0.f, 0.f};

    float idn[4], riq[2][4];
    float* wtile = s_sim + w * SHALF;

    if (PRE) {
        const ushort* qp0 = ebf + (size_t)qid0 * EMBED + quad * 8;
        const ushort* qp1 = ebf + (size_t)qid1 * EMBED + quad * 8;
        #pragma unroll
        for (int kk = 0; kk < 4; ++kk) {
            const bf16x8 a0 = *((const bf16x8*)(qp0 + kk * 32));
            const bf16x8 a1 = *((const bf16x8*)(qp1 + kk * 32));
            #pragma unroll
            for (int nt = 0; nt < 4; ++nt) {
                const bf16x8 bb = *((const bf16x8*)(ebf + (size_t)did[nt] * EMBED + quad * 8 + kk * 32));
                acc[0][nt] = __builtin_amdgcn_mfma_f32_16x16x32_bf16(a0, bb, acc[0][nt], 0, 0, 0);
                acc[1][nt] = __builtin_amdgcn_mfma_f32_16x16x32_bf16(a1, bb, acc[1][nt], 0, 0, 0);
            }
        }
        #pragma unroll
        for (int nt = 0; nt < 4; ++nt) idn[nt] = inorm[did[nt]];
        #pragma unroll
        for (int r = 0; r < 4; ++r) {
            riq[0][r] = inorm[qry[quad * 4 + r]];
            riq[1][r] = inorm[qry[16 + quad * 4 + r]];
        }
    } else {
        float qn2[2] = {0.f, 0.f}, dn2[4] = {0.f, 0.f, 0.f, 0.f};
        const float* qp0 = emb + (size_t)qid0 * EMBED + quad * 8;
        const float* qp1 = emb + (size_t)qid1 * EMBED + quad * 8;
        #pragma unroll
        for (int kk = 0; kk < 4; ++kk) {
            const bf16x8 a0 = cvt8(qp0 + kk * 32, qn2[0]);
            const bf16x8 a1 = cvt8(qp1 + kk * 32, qn2[1]);
            #pragma unroll
            for (int nt = 0; nt < 4; ++nt) {
                const bf16x8 bb = cvt8(emb + (size_t)did[nt] * EMBED + quad * 8 + kk * 32, dn2[nt]);
                acc[0][nt] = __builtin_amdgcn_mfma_f32_16x16x32_bf16(a0, bb, acc[0][nt], 0, 0, 0);
                acc[1][nt] = __builtin_amdgcn_mfma_f32_16x16x32_bf16(a1, bb, acc[1][nt], 0, 0, 0);
            }
        }
        #pragma unroll
        for (int i = 0; i < 2; ++i) {
            qn2[i] += __shfl_xor(qn2[i], 16);
            qn2[i] += __shfl_xor(qn2[i], 32);
        }
        #pragma unroll
        for (int nt = 0; nt < 4; ++nt) {
            dn2[nt] += __shfl_xor(dn2[nt], 16);
            dn2[nt] += __shfl_xor(dn2[nt], 32);
            idn[nt] = __builtin_amdgcn_rsqf(dn2[nt]);
        }
        #pragma unroll
        for (int r = 0; r < 4; ++r) {
            riq[0][r] = __builtin_amdgcn_rsqf(__shfl(qn2[0], quad * 4 + r));
            riq[1][r] = __builtin_amdgcn_rsqf(__shfl(qn2[1], quad * 4 + r));
        }
    }

    pool_half(wtile, acc[0], riq[0], idn, s_tot, 0,  l15, quad);
    pool_half(wtile, acc[1], riq[1], idn, s_tot, 16, l15, quad);
    __syncthreads();

    if (t < QLEN) {
        float c = 0.f;
        #pragma unroll
        for (int k = 0; k < KNUM; ++k) c += mlp_w[k] * log1pf(s_tot[t][k]);
        #pragma unroll
        for (int mm = 1; mm < 32; mm <<= 1) c += __shfl_xor(c, mm);
        if (t == 0) logits[pair * NB + b] = c;
    }
}

__global__ __launch_bounds__(256)
void knrm_combine(const float* __restrict__ logits, float* __restrict__ out)
{
    const int i = blockIdx.x * blockDim.x + threadIdx.x;
    if (i < NB) {
        const float d = logits[i] - logits[NB + i];
        out[i] = 1.f / (1.f + __expf(-d));
    }
}

extern "C" void kernel_launch(void* const* d_in, const int* in_sizes, int n_in,
                              void* d_out, int out_size, void* d_ws, size_t ws_size,
                              hipStream_t stream)
{
    const float* emb   = (const float*)d_in[0];
    const float* mlp_w = (const float*)d_in[1];
    // mlp_b (d_in[2]) unused: cancels in logits1 - logits2
    const int* q1 = (const int*)d_in[3];
    const int* d1 = (const int*)d_in[4];
    const int* q2 = (const int*)d_in[5];
    const int* d2 = (const int*)d_in[6];

    float* out = (float*)d_out;

    const size_t need = 2 * NB * 4                       // logits
                      + (size_t)VOCAB * 4                // inorm
                      + (size_t)VOCAB * EMBED * 2 + 256; // bf16 table
    if (ws_size >= need) {
        float*  logits = (float*)d_ws;
        float*  inorm  = logits + 2 * NB;
        ushort* ebf    = (ushort*)(inorm + VOCAB);
        cvt_table<<<VOCAB / 8, 256, 0, stream>>>(emb, ebf, inorm);
        knrm_pair4<<<dim3(NB, 2), 256, 0, stream>>>(ebf, inorm, mlp_w,
                                                    q1, d1, q2, d2, logits);
    } else {
        float* logits = (float*)d_ws;
        knrm_pair<false><<<dim3(NB, 2), 256, 0, stream>>>(emb, nullptr, nullptr, mlp_w,
                                                          q1, d1, q2, d2, logits);
    }
    knrm_combine<<<(NB + 255) / 256, 256, 0, stream>>>((float*)d_ws, out);
}

// Round 11
// 137.303 us; speedup vs baseline: 1.3531x; 1.0214x over previous
//
#include <hip/hip_runtime.h>
#include <math.h>
#include <stdint.h>

#define VOCAB 100000
#define NB    1024
#define QLEN  32
#define DLEN  256
#define EMBED 128
#define KNUM  11

typedef __attribute__((ext_vector_type(8))) short bf16x8;   // 8 bf16 = 4 VGPRs
typedef __attribute__((ext_vector_type(4))) float f32x4;

// Gaussian chain: mus -0.9..0.9 step 0.2 (sigma 0.1) + exact mu=1 sigma=.001
#define HALF_L2E 0.7213475204444817f   // 0.5*log2(e)
#define TWO_L2E  2.8853900817779268f   // 2*log2(e)
#define EM4      0.018315638888734179f // e^-4

// Wave-private sim half-tile: [m=16][n=64], row stride 68 (16B-aligned rows,
// 2-way bank aliasing = free per m136).
#define SSTR  68
#define SHALF (16 * SSTR)

// raw HW 2^x: one v_exp_f32 instead of the multi-instruction OCML exp2f
// (no fast-math in harness flags -> exp2f goes through __ocml_exp2_f32).
__device__ __forceinline__ float ex2(float x)
{
    float r;
    asm("v_exp_f32 %0, %1" : "=v"(r) : "v"(x));
    return r;
}

// ---------- prepass: fp32 table -> bf16 table + bf16-consistent inv-norms ----
__global__ __launch_bounds__(256)
void cvt_table(const float* __restrict__ emb, ushort* __restrict__ ebf,
               float* __restrict__ inorm)
{
    const int row = blockIdx.x * 8 + (threadIdx.x >> 5);
    const int l32 = threadIdx.x & 31;
    const float4 v = *((const float4*)(emb + (size_t)row * EMBED) + l32);
    union { float f; unsigned u; } x0, x1, x2, x3;
    x0.f = v.x; x1.f = v.y; x2.f = v.z; x3.f = v.w;
    const unsigned r0 = x0.u + 0x8000u, r1 = x1.u + 0x8000u;  // round-half-up
    const unsigned r2 = x2.u + 0x8000u, r3 = x3.u + 0x8000u;
    uint2 packed;
    packed.x = (r0 >> 16) | (r1 & 0xFFFF0000u);
    packed.y = (r2 >> 16) | (r3 & 0xFFFF0000u);
    *((uint2*)(ebf + (size_t)row * EMBED) + l32) = packed;
    x0.u = r0 & 0xFFFF0000u; x1.u = r1 & 0xFFFF0000u;
    x2.u = r2 & 0xFFFF0000u; x3.u = r3 & 0xFFFF0000u;
    float n = x0.f * x0.f + x1.f * x1.f + x2.f * x2.f + x3.f * x3.f;
    #pragma unroll
    for (int m = 1; m < 32; m <<= 1) n += __shfl_xor(n, m);
    if (l32 == 0) inorm[row] = __builtin_amdgcn_rsqf(n);
}

// ---------------------------------------------------------------------------
// fallback helper: fp32 -> bf16 frag + norm of rounded values
__device__ __forceinline__ bf16x8 cvt8(const float* p, float& nacc)
{
    uint4 a = *((const uint4*)p);
    uint4 b = *((const uint4*)(p + 4));
    unsigned u[8] = {a.x, a.y, a.z, a.w, b.x, b.y, b.z, b.w};
    bf16x8 r;
    #pragma unroll
    for (int i = 0; i < 8; ++i) {
        const unsigned q = u[i] + 0x8000u;
        r[i] = (short)(q >> 16);
        union { unsigned uu; float ff; } g; g.uu = q & 0xFFFF0000u;
        nacc = fmaf(g.ff, g.ff, nacc);
    }
    return r;
}

// pool one 16-row half-tile: write sims, exp-chain, reduce, atomic into s_tot
__device__ __forceinline__ void pool_half(float* __restrict__ wtile,
                                          const f32x4* __restrict__ a,   // [4] nt
                                          const float* __restrict__ riq, // [4] r
                                          const float* __restrict__ idn, // [4] nt
                                          float (*__restrict__ stot)[12],
                                          int mtbase, int l15, int quad)
{
    #pragma unroll
    for (int nt = 0; nt < 4; ++nt)
        #pragma unroll
        for (int r = 0; r < 4; ++r)
            wtile[(quad * 4 + r) * SSTR + nt * 16 + l15] = a[nt][r] * riq[r] * idn[nt];

    const float* rp = wtile + l15 * SSTR + quad * 16;   // row l15, chunk quad
    float ksum[KNUM];
    #pragma unroll
    for (int k = 0; k < KNUM; ++k) ksum[k] = 0.f;

    #pragma unroll
    for (int i = 0; i < 4; ++i) {
        const f32x4 sv = *((const f32x4*)(rp + 4 * i));
        #pragma unroll
        for (int e = 0; e < 4; ++e) {
            const float s  = sv[e];
            const float z  = fmaf(s, 10.f, -1.f);
            const float e0 = ex2(-HALF_L2E * (z * z));
            float ru = ex2(fmaf(z,  TWO_L2E, -TWO_L2E));
            float rd = ex2(fmaf(z, -TWO_L2E, -TWO_L2E));
            ksum[5] += e0;
            float tt = e0;
            tt *= ru; ksum[6] += tt; ru *= EM4;
            tt *= ru; ksum[7] += tt; ru *= EM4;
            tt *= ru; ksum[8] += tt; ru *= EM4;
            tt *= ru; ksum[9] += tt;
            tt = e0;
            tt *= rd; ksum[4] += tt; rd *= EM4;
            tt *= rd; ksum[3] += tt; rd *= EM4;
            tt *= rd; ksum[2] += tt; rd *= EM4;
            tt *= rd; ksum[1] += tt; rd *= EM4;
            tt *= rd; ksum[0] += tt;
            // exact kernel (sigma=.001): ==1 iff token match (bf16 self-sim
            // 1+-3e-6; non-match needs cos>0.995 ~ 11 sigma)
            ksum[10] += (s > 0.995f) ? 1.f : 0.f;
        }
    }
    #pragma unroll
    for (int k = 0; k < KNUM; ++k) {
        ksum[k] += __shfl_xor(ksum[k], 16);
        ksum[k] += __shfl_xor(ksum[k], 32);
    }
    if (quad == 0) {
        #pragma unroll
        for (int k = 0; k < KNUM; ++k)
            atomicAdd(&stot[mtbase + l15][k], ksum[k]);
    }
}

// ---------------------------------------------------------------------------
// Round-11: round-4 structure (best verified: 50.8us dispatch, 140.2us total)
// with ONE change: raw v_exp_f32 in the pool chain (3 per sim) instead of
// OCML exp2f. Everything else byte-identical to r4/r10.
__global__ __launch_bounds__(256, 3)
void knrm_pair4(const ushort* __restrict__ ebf,
                const float* __restrict__ inorm,
                const float* __restrict__ mlp_w,
                const int* __restrict__ q1, const int* __restrict__ d1,
                const int* __restrict__ q2, const int* __restrict__ d2,
                float* __restrict__ logits)
{
    const int b    = blockIdx.x;
    const int pair = blockIdx.y;
    const int t    = threadIdx.x;
    const int w    = t >> 6;        // wave id: doc tiles w*4..w*4+3
    const int l15  = t & 15;
    const int quad = (t & 63) >> 4;

    const int* __restrict__ qry = (pair == 0 ? q1 : q2) + b * QLEN;
    const int* __restrict__ doc = (pair == 0 ? d1 : d2) + b * DLEN;

    __shared__ __align__(16) float s_sim[4 * SHALF];   // 17408 B wave-private
    __shared__ float s_tot[QLEN][12];                  // 1536 B

    // ---- ids (independent, oldest vmem) ----
    const int qid0 = qry[l15], qid1 = qry[l15 + 16];
    int did[4];
    #pragma unroll
    for (int j = 0; j < 4; ++j) did[j] = doc[(w * 4 + j) * 16 + l15];

    // ---- all 24 fragment gathers, issued before any compute ----
    bf16x8 a0[4], a1[4], bbf[4][4];
    {
        const ushort* qp0 = ebf + (size_t)qid0 * EMBED + quad * 8;
        const ushort* qp1 = ebf + (size_t)qid1 * EMBED + quad * 8;
        #pragma unroll
        for (int kk = 0; kk < 4; ++kk) {
            a0[kk] = *(const bf16x8*)(qp0 + kk * 32);
            a1[kk] = *(const bf16x8*)(qp1 + kk * 32);
        }
        #pragma unroll
        for (int j = 0; j < 4; ++j) {
            const ushort* dp = ebf + (size_t)did[j] * EMBED + quad * 8;
            #pragma unroll
            for (int kk = 0; kk < 4; ++kk)
                bbf[j][kk] = *(const bf16x8*)(dp + kk * 32);
        }
    }
    // norm gathers: consumed only in pooling -> stay in flight through MFMA
    float idn[4];
    #pragma unroll
    for (int j = 0; j < 4; ++j) idn[j] = inorm[did[j]];
    float riq[2][4];
    #pragma unroll
    for (int r = 0; r < 4; ++r) {
        riq[0][r] = inorm[qry[quad * 4 + r]];
        riq[1][r] = inorm[qry[16 + quad * 4 + r]];
    }

    // zero s_tot while the gathers fly
    #pragma unroll
    for (int i = t; i < QLEN * 12; i += 256) ((float*)s_tot)[i] = 0.f;

    // ---- pin: loads can't sink below (data dep), MFMAs can't hoist above ----
    #pragma unroll
    for (int kk = 0; kk < 4; ++kk)
        asm volatile("" :: "v"(a0[kk]), "v"(a1[kk]));
    #pragma unroll
    for (int j = 0; j < 4; ++j)
        asm volatile("" :: "v"(bbf[j][0]), "v"(bbf[j][1]),
                          "v"(bbf[j][2]), "v"(bbf[j][3]));
    __builtin_amdgcn_sched_barrier(0);

    // ---- MFMA: 32 q-rows x 64 doc-cols x K=128 per wave ----
    f32x4 acc[2][4];
    #pragma unroll
    for (int mt = 0; mt < 2; ++mt)
        #pragma unroll
        for (int j = 0; j < 4; ++j)
            acc[mt][j] = (f32x4){0.f, 0.f, 0.f, 0.f};
    #pragma unroll
    for (int kk = 0; kk < 4; ++kk)
        #pragma unroll
        for (int j = 0; j < 4; ++j) {
            acc[0][j] = __builtin_amdgcn_mfma_f32_16x16x32_bf16(a0[kk], bbf[j][kk], acc[0][j], 0, 0, 0);
            acc[1][j] = __builtin_amdgcn_mfma_f32_16x16x32_bf16(a1[kk], bbf[j][kk], acc[1][j], 0, 0, 0);
        }

    __syncthreads();        // s_tot zeros visible before pooling atomics

    float* wtile = s_sim + w * SHALF;
    pool_half(wtile, acc[0], riq[0], idn, s_tot, 0,  l15, quad);
    pool_half(wtile, acc[1], riq[1], idn, s_tot, 16, l15, quad);
    __syncthreads();

    if (t < QLEN) {
        float c = 0.f;
        #pragma unroll
        for (int k = 0; k < KNUM; ++k) c += mlp_w[k] * log1pf(s_tot[t][k]);
        #pragma unroll
        for (int mm = 1; mm < 32; mm <<= 1) c += __shfl_xor(c, mm);
        if (t == 0) logits[pair * NB + b] = c;   // mlp bias cancels in l1-l2
    }
}

// Legacy kernel, kept as the small-workspace fallback (instantiated <false>).
template<bool PRE>
__global__ __launch_bounds__(256, 4)
void knrm_pair(const float* __restrict__ emb,
               const ushort* __restrict__ ebf,
               const float* __restrict__ inorm,
               const float* __restrict__ mlp_w,
               const int* __restrict__ q1, const int* __restrict__ d1,
               const int* __restrict__ q2, const int* __restrict__ d2,
               float* __restrict__ logits)
{
    const int b    = blockIdx.x;
    const int pair = blockIdx.y;
    const int t    = threadIdx.x;
    const int w    = t >> 6;
    const int l15  = t & 15;
    const int quad = (t & 63) >> 4;

    const int* __restrict__ qry = (pair == 0 ? q1 : q2) + b * QLEN;
    const int* __restrict__ doc = (pair == 0 ? d1 : d2) + b * DLEN;

    __shared__ __align__(16) float s_sim[4 * SHALF];
    __shared__ float s_tot[QLEN][12];

    #pragma unroll
    for (int i = t; i < QLEN * 12; i += 256) ((float*)s_tot)[i] = 0.f;
    __syncthreads();

    const int qid0 = qry[l15], qid1 = qry[l15 + 16];
    int did[4];
    #pragma unroll
    for (int nt = 0; nt < 4; ++nt) did[nt] = doc[(w * 4 + nt) * 16 + l15];

    f32x4 acc[2][4];
    #pragma unroll
    for (int mt = 0; mt < 2; ++mt)
        #pragma unroll
        for (int nt = 0; nt < 4; ++nt)
            acc[mt][nt] = (f32x4){0.f, 0.f, 0.f, 0.f};

    float idn[4], riq[2][4];
    float* wtile = s_sim + w * SHALF;

    if (PRE) {
        const ushort* qp0 = ebf + (size_t)qid0 * EMBED + quad * 8;
        const ushort* qp1 = ebf + (size_t)qid1 * EMBED + quad * 8;
        #pragma unroll
        for (int kk = 0; kk < 4; ++kk) {
            const bf16x8 a0 = *((const bf16x8*)(qp0 + kk * 32));
            const bf16x8 a1 = *((const bf16x8*)(qp1 + kk * 32));
            #pragma unroll
            for (int nt = 0; nt < 4; ++nt) {
                const bf16x8 bb = *((const bf16x8*)(ebf + (size_t)did[nt] * EMBED + quad * 8 + kk * 32));
                acc[0][nt] = __builtin_amdgcn_mfma_f32_16x16x32_bf16(a0, bb, acc[0][nt], 0, 0, 0);
                acc[1][nt] = __builtin_amdgcn_mfma_f32_16x16x32_bf16(a1, bb, acc[1][nt], 0, 0, 0);
            }
        }
        #pragma unroll
        for (int nt = 0; nt < 4; ++nt) idn[nt] = inorm[did[nt]];
        #pragma unroll
        for (int r = 0; r < 4; ++r) {
            riq[0][r] = inorm[qry[quad * 4 + r]];
            riq[1][r] = inorm[qry[16 + quad * 4 + r]];
        }
    } else {
        float qn2[2] = {0.f, 0.f}, dn2[4] = {0.f, 0.f, 0.f, 0.f};
        const float* qp0 = emb + (size_t)qid0 * EMBED + quad * 8;
        const float* qp1 = emb + (size_t)qid1 * EMBED + quad * 8;
        #pragma unroll
        for (int kk = 0; kk < 4; ++kk) {
            const bf16x8 a0 = cvt8(qp0 + kk * 32, qn2[0]);
            const bf16x8 a1 = cvt8(qp1 + kk * 32, qn2[1]);
            #pragma unroll
            for (int nt = 0; nt < 4; ++nt) {
                const bf16x8 bb = cvt8(emb + (size_t)did[nt] * EMBED + quad * 8 + kk * 32, dn2[nt]);
                acc[0][nt] = __builtin_amdgcn_mfma_f32_16x16x32_bf16(a0, bb, acc[0][nt], 0, 0, 0);
                acc[1][nt] = __builtin_amdgcn_mfma_f32_16x16x32_bf16(a1, bb, acc[1][nt], 0, 0, 0);
            }
        }
        #pragma unroll
        for (int i = 0; i < 2; ++i) {
            qn2[i] += __shfl_xor(qn2[i], 16);
            qn2[i] += __shfl_xor(qn2[i], 32);
        }
        #pragma unroll
        for (int nt = 0; nt < 4; ++nt) {
            dn2[nt] += __shfl_xor(dn2[nt], 16);
            dn2[nt] += __shfl_xor(dn2[nt], 32);
            idn[nt] = __builtin_amdgcn_rsqf(dn2[nt]);
        }
        #pragma unroll
        for (int r = 0; r < 4; ++r) {
            riq[0][r] = __builtin_amdgcn_rsqf(__shfl(qn2[0], quad * 4 + r));
            riq[1][r] = __builtin_amdgcn_rsqf(__shfl(qn2[1], quad * 4 + r));
        }
    }

    pool_half(wtile, acc[0], riq[0], idn, s_tot, 0,  l15, quad);
    pool_half(wtile, acc[1], riq[1], idn, s_tot, 16, l15, quad);
    __syncthreads();

    if (t < QLEN) {
        float c = 0.f;
        #pragma unroll
        for (int k = 0; k < KNUM; ++k) c += mlp_w[k] * log1pf(s_tot[t][k]);
        #pragma unroll
        for (int mm = 1; mm < 32; mm <<= 1) c += __shfl_xor(c, mm);
        if (t == 0) logits[pair * NB + b] = c;
    }
}

__global__ __launch_bounds__(256)
void knrm_combine(const float* __restrict__ logits, float* __restrict__ out)
{
    const int i = blockIdx.x * blockDim.x + threadIdx.x;
    if (i < NB) {
        const float d = logits[i] - logits[NB + i];
        out[i] = 1.f / (1.f + __expf(-d));
    }
}

extern "C" void kernel_launch(void* const* d_in, const int* in_sizes, int n_in,
                              void* d_out, int out_size, void* d_ws, size_t ws_size,
                              hipStream_t stream)
{
    const float* emb   = (const float*)d_in[0];
    const float* mlp_w = (const float*)d_in[1];
    // mlp_b (d_in[2]) unused: cancels in logits1 - logits2
    const int* q1 = (const int*)d_in[3];
    const int* d1 = (const int*)d_in[4];
    const int* q2 = (const int*)d_in[5];
    const int* d2 = (const int*)d_in[6];

    float* out = (float*)d_out;

    const size_t need = 2 * NB * 4                       // logits
                      + (size_t)VOCAB * 4                // inorm
                      + (size_t)VOCAB * EMBED * 2 + 256; // bf16 table
    if (ws_size >= need) {
        float*  logits = (float*)d_ws;
        float*  inorm  = logits + 2 * NB;
        ushort* ebf    = (ushort*)(inorm + VOCAB);
        cvt_table<<<VOCAB / 8, 256, 0, stream>>>(emb, ebf, inorm);
        knrm_pair4<<<dim3(NB, 2), 256, 0, stream>>>(ebf, inorm, mlp_w,
                                                    q1, d1, q2, d2, logits);
    } else {
        float* logits = (float*)d_ws;
        knrm_pair<false><<<dim3(NB, 2), 256, 0, stream>>>(emb, nullptr, nullptr, mlp_w,
                                                          q1, d1, q2, d2, logits);
    }
    knrm_combine<<<(NB + 255) / 256, 256, 0, stream>>>((float*)d_ws, out);
}